// Round 14
// baseline (671.944 us; speedup 1.0000x reference)
//
#include <hip/hip_runtime.h>
#include <cstdint>
#include <cstddef>

#define N_TOT   147456      // 9*128*128
#define K_PRE   6000
#define K_POST  300
#define CAP     32768       // candidate cap (expected ~9.2K)
#define MW      188         // 6016 bits per mask row -> 188 u32 words
#define ROWS_PAD 6016
#define NCHUNK  94
#define CT      128         // mask columns per tile
#define NTILE   576         // N_TOT/256
#define MTILES  1128        // 24 row-blocks * 47 col-tiles... (indexed rb,cb below)
#define ROWB    24
#define COLB    47
#define G       16          // candidates ranked per BLOCK
#define NB      1024        // persistent grid: 4 blocks/CU guaranteed by resources

struct Params {
    const float* scores; const float* deltas; float* out;
    uint32_t* hist; uint32_t* meta; uint32_t* bars;
    uint32_t* keys; uint64_t* cand;
    float4* P; uint64_t* yk; float4* OP; float4* Q; float* Bnd;
    uint32_t* mask;
};

__constant__ float c_sizes[9] = {4.f,8.f,12.f,16.f,24.f,32.f,48.f,64.f,96.f};

// Bit-exact replication of reference box math (anchor + delta, clip).
__device__ __forceinline__ void compute_box(int idx, const float* __restrict__ deltas,
                                            float& px1, float& py1, float& pw, float& ph) {
    int a   = idx >> 14;
    int rem = idx & 16383;
    int h   = rem >> 7;
    int w   = rem & 127;
    float s    = c_sizes[a];
    float half = s * 0.5f;
    const float4 d = *(const float4*)(deltas + (size_t)a * 65536 + (size_t)rem * 4);
    float b0 = (((float)h + 0.5f) - half) + d.x;
    float b1 = (((float)w + 0.5f) - half) + d.y;
    float b2 = s + d.z;
    float b3 = s + d.w;
    b0 = fmaxf(b0, 0.0f); b1 = fmaxf(b1, 0.0f);
    b2 = fmaxf(b2, 0.0f); b3 = fmaxf(b3, 0.0f);
    float x1 = b0, y1 = b1;
    float x2 = b0 + b2, y2 = b1 + b3;
    x1 = fminf(x1, 128.0f); y1 = fminf(y1, 128.0f);
    x2 = fminf(x2, 128.0f); y2 = fminf(y2, 128.0f);
    px1 = x1; py1 = y1; pw = x2 - x1; ph = y2 - y1;
}

__device__ __forceinline__ uint32_t waveReduceSum(uint32_t v) {
    #pragma unroll
    for (int o = 32; o > 0; o >>= 1) v += __shfl_xor(v, o, 64);
    return v;
}

// One-shot software grid barrier: arrive (ACQ_REL) then spin (ACQUIRE) until
// all NB blocks arrived. Counters memset-zeroed each call -> no reset/ABA.
// s_sleep backoff keeps 1023 pollers from hammering the counter's L2 line.
__device__ __forceinline__ void gbar(uint32_t* cnt, int nb) {
    __syncthreads();
    if (threadIdx.x == 0) {
        __hip_atomic_fetch_add(cnt, 1u, __ATOMIC_ACQ_REL, __HIP_MEMORY_SCOPE_AGENT);
        while (__hip_atomic_load(cnt, __ATOMIC_ACQUIRE, __HIP_MEMORY_SCOPE_AGENT)
               < (uint32_t)nb) {
            #pragma unroll
            for (int i = 0; i < 8; i++) __builtin_amdgcn_s_sleep(8);
        }
    }
    __syncthreads();
}

__global__ void __launch_bounds__(256, 4) k_fused(Params p) {
    __shared__ __align__(16) uint32_t sh[4352];   // 17.4 KB, aliased per phase
    const int tid = threadIdx.x;
    const int bid = blockIdx.x;
    const int nb  = gridDim.x;

    // ---------------- P1: keys + histogram ----------------
    for (int i = tid; i < 4096; i += 256) sh[i] = 0u;
    __syncthreads();
    for (int t = bid; t < NTILE; t += nb) {
        int idx = t * 256 + tid;
        float px1, py1, pw, ph;
        compute_box(idx, p.deltas, px1, py1, pw, ph);
        bool keep = (pw >= 3.0f) && (ph >= 3.0f);
        uint32_t key = keep ? __float_as_uint(p.scores[idx]) : 0u;
        p.keys[idx] = key;
        atomicAdd(&sh[key >> 20], 1u);
    }
    __syncthreads();
    for (int i = tid; i < 4096; i += 256) {
        uint32_t v = sh[i];
        if (v) atomicAdd(&p.hist[i], v);
    }
    gbar(&p.bars[0], nb);

    // ---------------- P2: per-block findbin (suffix-scan) + compact ----------
    {
        uint32_t* lh  = sh;          // [0..4095]
        uint32_t* seg = sh + 4096;   // [0..255]
        for (int i = tid; i < 4096; i += 256) lh[i] = p.hist[i];
        __syncthreads();
        uint32_t s = 0;
        #pragma unroll
        for (int q = 0; q < 16; q++) s += lh[tid * 16 + q];
        seg[tid] = s;
        __syncthreads();
        for (int off = 1; off < 256; off <<= 1) {
            uint32_t v = seg[tid];
            if (tid + off < 256) v += seg[tid + off];
            __syncthreads();
            seg[tid] = v;
            __syncthreads();
        }
        uint32_t St  = seg[tid];
        uint32_t St1 = (tid < 255) ? seg[tid + 1] : 0u;
        if (St >= K_PRE && St1 < K_PRE) {
            uint32_t c2 = St1;
            uint32_t bstar = 0u;
            for (int q = 15; q >= 0; q--) {
                c2 += lh[tid * 16 + q];
                if (c2 >= K_PRE) { bstar = (uint32_t)(tid * 16 + q); break; }
            }
            sh[4200] = bstar;
        }
        if (tid == 0 && seg[0] < K_PRE) sh[4200] = 0u;
        __syncthreads();
        uint32_t bstar = sh[4200];
        for (int t = bid; t < NTILE; t += nb) {
            int idx = t * 256 + tid;
            uint32_t key = p.keys[idx];
            if ((key >> 20) >= bstar) {
                uint32_t pos = atomicAdd(p.meta + 1, 1u);
                if (pos < CAP) p.cand[pos] = ((uint64_t)key << 32) | (uint32_t)(~(uint32_t)idx);
            }
        }
    }
    gbar(&p.bars[1], nb);

    // ---------------- P3: rank by score (16 cands/block) + props/ykey --------
    {
        uint32_t (*part)[G] = (uint32_t(*)[G])sh;
        uint32_t C = p.meta[1];
        if (C > CAP) C = CAP;
        uint32_t nGroups = (C + G - 1) / G;
        int wave = tid >> 6, lane = tid & 63;
        for (uint32_t g = bid; g < nGroups; g += nb) {
            uint32_t b = g * G;
            uint64_t m[G];
            uint32_t cnt[G];
            #pragma unroll
            for (int q = 0; q < G; q++) {
                m[q] = (b + q < C) ? p.cand[b + q] : ~0ull;
                cnt[q] = 0u;
            }
            for (uint32_t j0 = 0; j0 < C; j0 += 1024) {
                uint32_t ja = j0 + tid, jb = ja + 256, jc = ja + 512, jd = ja + 768;
                uint64_t ka = (ja < C) ? p.cand[ja] : 0ull;
                uint64_t kb = (jb < C) ? p.cand[jb] : 0ull;
                uint64_t kc = (jc < C) ? p.cand[jc] : 0ull;
                uint64_t kd = (jd < C) ? p.cand[jd] : 0ull;
                #pragma unroll
                for (int q = 0; q < G; q++)
                    cnt[q] += (uint32_t)(ka > m[q]) + (uint32_t)(kb > m[q])
                            + (uint32_t)(kc > m[q]) + (uint32_t)(kd > m[q]);
            }
            #pragma unroll
            for (int q = 0; q < G; q++) cnt[q] = waveReduceSum(cnt[q]);
            if (lane == 0) {
                #pragma unroll
                for (int q = 0; q < G; q++) part[wave][q] = cnt[q];
            }
            __syncthreads();
            if (tid < G && b + tid < C) {
                uint32_t r = part[0][tid] + part[1][tid] + part[2][tid] + part[3][tid];
                if (r < K_PRE) {
                    int idx = (int)(~((uint32_t)p.cand[b + tid]));
                    float px1, py1, pw, ph;
                    compute_box(idx, p.deltas, px1, py1, pw, ph);
                    p.P[r] = make_float4(px1, py1, pw, ph);
                    float y2 = py1 + ph;
                    p.yk[r] = ((uint64_t)__float_as_uint(y2) << 32) | (uint32_t)(~r);
                }
            }
            __syncthreads();
        }
    }
    gbar(&p.bars[2], nb);

    // ---------------- P4: stable y2-desc rank + div-free boundary ------------
    // pred( round(d/area) >= 0.7f ) <=> d >= Bnd; M = 0.7f - 2^-25; M*area
    // exact in double; Bnd = smallest fp32 > M*area.
    {
        uint32_t (*part)[G] = (uint32_t(*)[G])sh;
        int wave = tid >> 6, lane = tid & 63;
        for (uint32_t g = bid; g < (K_PRE / G); g += nb) {   // 375 groups
            uint32_t b = g * G;
            uint64_t m[G];
            uint32_t cnt[G];
            #pragma unroll
            for (int q = 0; q < G; q++) {
                m[q] = p.yk[b + q];
                cnt[q] = 0u;
            }
            for (uint32_t j0 = 0; j0 < K_PRE; j0 += 1024) {
                uint32_t ja = j0 + tid, jb = ja + 256, jc = ja + 512, jd = ja + 768;
                uint64_t ka = (ja < K_PRE) ? p.yk[ja] : 0ull;
                uint64_t kb = (jb < K_PRE) ? p.yk[jb] : 0ull;
                uint64_t kc = (jc < K_PRE) ? p.yk[jc] : 0ull;
                uint64_t kd = (jd < K_PRE) ? p.yk[jd] : 0ull;
                #pragma unroll
                for (int q = 0; q < G; q++)
                    cnt[q] += (uint32_t)(ka > m[q]) + (uint32_t)(kb > m[q])
                            + (uint32_t)(kc > m[q]) + (uint32_t)(kd > m[q]);
            }
            #pragma unroll
            for (int q = 0; q < G; q++) cnt[q] = waveReduceSum(cnt[q]);
            if (lane == 0) {
                #pragma unroll
                for (int q = 0; q < G; q++) part[wave][q] = cnt[q];
            }
            __syncthreads();
            if (tid < G) {
                uint32_t r = part[0][tid] + part[1][tid] + part[2][tid] + part[3][tid];
                float4 pp = p.P[b + tid];
                p.OP[r] = pp;
                float x1 = pp.x, y1 = pp.y;
                float x2 = x1 + pp.z, y2 = y1 + pp.w;
                float area = fmaxf((x2 - x1) * (y2 - y1), 1e-6f);
                p.Q[r] = make_float4(x1, y1, x2, y2);
                const double Mc = (double)0.7f - 0x1.0p-25;
                double c = Mc * (double)area;       // exact
                float Bf = (float)c;
                if (!((double)Bf > c)) Bf = __int_as_float(__float_as_int(Bf) + 1);
                p.Bnd[r] = Bf;
            }
            __syncthreads();
        }
    }
    gbar(&p.bars[3], nb);

    // ---------------- P5: suppression bitmask (tiled, div-free) --------------
    {
        float4* qs = (float4*)sh;          // 128 * 16 B
        float*  bs = (float*)(sh + 512);   // 128 * 4 B
        for (int t = bid; t < ROWB * COLB; t += nb) {
            int rb = t % ROWB, cb = t / ROWB;
            int i  = rb * 256 + tid;
            int c0 = cb * CT;
            int ncols = min(CT, K_PRE - c0);
            __syncthreads();
            if (tid < ncols) {
                qs[tid] = p.Q[c0 + tid];
                bs[tid] = p.Bnd[c0 + tid];
            }
            __syncthreads();
            bool rowok = (i < K_PRE);
            float4 qi = rowok ? p.Q[i] : make_float4(0.f, 0.f, 0.f, 0.f);
            int nw = (ncols + 31) >> 5;
            for (int w = 0; w < nw; w++) {
                uint32_t bits = 0u;
                int jb = w * 32;
                int jn = min(32, ncols - jb);
                #pragma unroll 8
                for (int b = 0; b < jn; b++) {
                    int j = jb + b;
                    float4 qj = qs[j];
                    float iw = fminf(qi.z, qj.z) - fmaxf(qi.x, qj.x) + 1.0f;
                    iw = fmaxf(iw, 0.0f);
                    float ih = fminf(qi.w, qj.w) - fmaxf(qi.y, qj.y) + 1.0f;
                    ih = fmaxf(ih, 0.0f);
                    float d = iw * ih;
                    bits |= (d >= bs[j]) ? (1u << b) : 0u;
                }
                if (rowok) {
                    int gj = c0 + jb;
                    uint32_t selfo = (uint32_t)(i - gj);
                    if (selfo < 32u) bits &= ~(1u << selfo);
                    p.mask[(size_t)i * MW + (gj >> 5)] = bits;
                }
            }
        }
    }
    gbar(&p.bars[4], nb);

    // ---------------- P6: serial active scan + validity + emit (block 0) -----
    if (bid == 0) {
        uint32_t* rem  = sh;          // [0..187]
        uint32_t* sidx = sh + 192;    // [0..63]
        uint32_t* svL  = sh + 256;    // [0..187]
        uint32_t* pref = sh + 448;    // [0..187]
        // sh[640] = nsSh
        for (int i = tid; i < MW; i += 256) rem[i] = 0u;
        for (int i = tid; i < K_POST * 4; i += 256) p.out[i] = 0.0f;
        __syncthreads();
        uint2 mr = make_uint2(0u, 0u);
        if (tid < 64) mr = *(const uint2*)(p.mask + (size_t)tid * MW);   // chunk 0
        for (int c = 0; c < NCHUNK; c++) {
            int base = c * 64;
            int rows = min(64, K_PRE - base);
            if (tid < 64) {
                uint64_t v = ~(((uint64_t)rem[2 * c + 1] << 32) | (uint64_t)rem[2 * c]);
                if (rows < 64) v &= ((1ull << rows) - 1ull);
                uint64_t work = v, surv = 0ull;
                while (work) {                      // leader iteration
                    int k = __ffsll((unsigned long long)work) - 1;
                    surv |= 1ull << k;
                    uint64_t rowk =
                        ((uint64_t)(uint32_t)__builtin_amdgcn_readlane((int)mr.y, k) << 32)
                      |  (uint64_t)(uint32_t)__builtin_amdgcn_readlane((int)mr.x, k);
                    work &= ~rowk;
                    work &= ~(1ull << k);
                }
                uint32_t ns = (uint32_t)__popcll(surv);
                if (tid == 0) {
                    svL[2 * c]     = (uint32_t)surv;
                    svL[2 * c + 1] = (uint32_t)(surv >> 32);
                    sh[640] = ns;
                }
                if ((surv >> tid) & 1ull) {
                    uint32_t pr = __popcll(surv & ((1ull << tid) - 1ull));
                    sidx[pr] = (uint32_t)(base + tid);
                }
                if (surv) {         // pad sidx to x16 with first survivor (OR-idempotent)
                    uint32_t nsPad = (ns + 15u) & ~15u;
                    uint32_t first = (uint32_t)base +
                                     (uint32_t)(__ffsll((unsigned long long)surv) - 1);
                    if ((uint32_t)tid >= ns && (uint32_t)tid < nsPad) sidx[tid] = first;
                }
                if (c + 1 < NCHUNK)
                    mr = *(const uint2*)(p.mask + (size_t)(base + 64 + tid) * MW + 2 * (c + 1));
            }
            __syncthreads();
            int w = tid - 64;
            if (w >= 0 && w < MW) {
                uint32_t nsPad = (sh[640] + 15u) & ~15u;
                uint32_t acc = rem[w];
                for (uint32_t t2 = 0; t2 < nsPad; t2 += 16) {
                    uint32_t r[16];
                    #pragma unroll
                    for (int q = 0; q < 16; q++)
                        r[q] = p.mask[(size_t)sidx[t2 + q] * MW + w];
                    uint32_t o = 0u;
                    #pragma unroll
                    for (int q = 0; q < 16; q++) o |= r[q];
                    acc |= o;
                }
                rem[w] = acc;
            }
            __syncthreads();
        }
        if (tid < MW) {
            uint32_t vv = svL[tid] & ~rem[tid];
            if (tid == MW - 1) vv &= 0xFFFFu;
            rem[tid] = vv;
        }
        __syncthreads();
        if (tid == 0) {
            uint32_t run = 0;
            for (int w2 = 0; w2 < MW; w2++) { pref[w2] = run; run += (uint32_t)__popc(rem[w2]); }
        }
        __syncthreads();
        if (tid < MW) {
            uint32_t b = rem[tid];
            uint32_t r = pref[tid];
            int basebit = tid * 32;
            while (b && r < K_POST) {
                int bit = __ffs(b) - 1;
                b &= b - 1u;
                float4 pp = p.OP[basebit + bit];
                *(float4*)(p.out + (size_t)r * 4) = pp;
                r++;
            }
        }
    }
}

extern "C" void kernel_launch(void* const* d_in, const int* in_sizes, int n_in,
                              void* d_out, int out_size, void* d_ws, size_t ws_size,
                              hipStream_t stream) {
    (void)in_sizes; (void)n_in; (void)out_size; (void)ws_size;
    char* ws = (char*)d_ws;
    size_t off = 0;
    auto alloc = [&](size_t bytes) -> void* {
        void* pp = ws + off;
        off += (bytes + 255) & ~(size_t)255;
        return pp;
    };
    Params p;
    p.scores = (const float*)d_in[0];
    p.deltas = (const float*)d_in[1];
    p.out    = (float*)d_out;
    p.hist  = (uint32_t*)alloc(4096 * 4);   // hist+meta+bars contiguous: one memset
    p.meta  = (uint32_t*)alloc(64);
    p.bars  = (uint32_t*)alloc(64);
    size_t zbytes = off;                     // 16384+256+256 = 16896 B
    p.keys  = (uint32_t*)alloc((size_t)N_TOT * 4);
    p.cand  = (uint64_t*)alloc((size_t)CAP * 8);
    p.P     = (float4*)alloc((size_t)K_PRE * 16);
    p.yk    = (uint64_t*)alloc((size_t)K_PRE * 8);
    p.OP    = (float4*)alloc((size_t)K_PRE * 16);
    p.Q     = (float4*)alloc((size_t)K_PRE * 16);
    p.Bnd   = (float*)alloc((size_t)K_PRE * 4);
    p.mask  = (uint32_t*)alloc((size_t)ROWS_PAD * MW * 4);   // ~4.5 MB

    hipMemsetAsync(p.hist, 0, zbytes, stream);   // hist + meta + barrier counters
    k_fused<<<NB, 256, 0, stream>>>(p);
}

// Round 15
// 377.511 us; speedup vs baseline: 1.7799x; 1.7799x over previous
//
#include <hip/hip_runtime.h>
#include <hip/hip_cooperative_groups.h>
#include <cstdint>
#include <cstddef>

namespace cg = cooperative_groups;

#define N_TOT   147456      // 9*128*128
#define K_PRE   6000
#define K_POST  300
#define CAP     32768       // candidate cap (expected ~9.2K)
#define MW      188         // 6016 bits per mask row -> 188 u32 words
#define ROWS_PAD 6016
#define NCHUNK  94
#define CT      128         // mask columns per tile
#define ROWB2   6           // ceil(6000/1024) row blocks in P5
#define COLB    47
#define G       16          // candidates ranked per BLOCK
#define NB      256         // cooperative grid (1 block/CU, validated in R5)
#define NT      1024        // threads/block -> 16 waves/CU (R5 had only 4)

struct Params {
    const float* scores; const float* deltas; float* out;
    uint32_t* hist; uint32_t* meta;
    uint32_t* keys; uint64_t* cand;
    float4* P; uint64_t* yk; float4* OP; float4* Q; float* Bnd;
    uint32_t* mask;
};

__constant__ float c_sizes[9] = {4.f,8.f,12.f,16.f,24.f,32.f,48.f,64.f,96.f};

// Bit-exact replication of reference box math (anchor + delta, clip).
__device__ __forceinline__ void compute_box(int idx, const float* __restrict__ deltas,
                                            float& px1, float& py1, float& pw, float& ph) {
    int a   = idx >> 14;
    int rem = idx & 16383;
    int h   = rem >> 7;
    int w   = rem & 127;
    float s    = c_sizes[a];
    float half = s * 0.5f;
    const float4 d = *(const float4*)(deltas + (size_t)a * 65536 + (size_t)rem * 4);
    float b0 = (((float)h + 0.5f) - half) + d.x;
    float b1 = (((float)w + 0.5f) - half) + d.y;
    float b2 = s + d.z;
    float b3 = s + d.w;
    b0 = fmaxf(b0, 0.0f); b1 = fmaxf(b1, 0.0f);
    b2 = fmaxf(b2, 0.0f); b3 = fmaxf(b3, 0.0f);
    float x1 = b0, y1 = b1;
    float x2 = b0 + b2, y2 = b1 + b3;
    x1 = fminf(x1, 128.0f); y1 = fminf(y1, 128.0f);
    x2 = fminf(x2, 128.0f); y2 = fminf(y2, 128.0f);
    px1 = x1; py1 = y1; pw = x2 - x1; ph = y2 - y1;
}

__device__ __forceinline__ uint32_t waveReduceSum(uint32_t v) {
    #pragma unroll
    for (int o = 32; o > 0; o >>= 1) v += __shfl_xor(v, o, 64);
    return v;
}

__global__ void __launch_bounds__(NT) k_all(Params p) {
    __shared__ __align__(16) uint32_t sh[4608];   // 18.4 KB, aliased per phase
    cg::grid_group grid = cg::this_grid();
    const int tid  = threadIdx.x;
    const int bid  = blockIdx.x;
    const int gtid = bid * NT + tid;              // 0..262143

    // ---------------- P0: zero out/hist/meta (replaces host memset) ----------
    if (gtid < 4096) p.hist[gtid] = 0u;
    if (gtid < 16)   p.meta[gtid] = 0u;
    if (gtid < K_POST * 4) p.out[gtid] = 0.0f;
    grid.sync();                                                    // S0

    // ---------------- P1: keys + histogram ----------------
    for (int i = tid; i < 4096; i += NT) sh[i] = 0u;
    __syncthreads();
    if (gtid < N_TOT) {
        float px1, py1, pw, ph;
        compute_box(gtid, p.deltas, px1, py1, pw, ph);
        bool keep = (pw >= 3.0f) && (ph >= 3.0f);
        uint32_t key = keep ? __float_as_uint(p.scores[gtid]) : 0u;
        p.keys[gtid] = key;
        atomicAdd(&sh[key >> 20], 1u);
    }
    __syncthreads();
    for (int i = tid; i < 4096; i += NT) {
        uint32_t v = sh[i];
        if (v) atomicAdd(&p.hist[i], v);
    }
    grid.sync();                                                    // S1

    // ---------------- P2: per-block findbin (suffix-scan) + compact ----------
    {
        uint32_t* lh  = sh;          // [0..4095]
        uint32_t* seg = sh + 4096;   // [4096..4351]
        // bstar lives at sh[4400] -- DISTINCT from seg (R14 had an alias race)
        for (int i = tid; i < 4096; i += NT) lh[i] = p.hist[i];
        __syncthreads();
        if (tid < 256) {
            uint32_t s = 0;
            #pragma unroll
            for (int q = 0; q < 16; q++) s += lh[tid * 16 + q];
            seg[tid] = s;
        }
        __syncthreads();
        for (int off = 1; off < 256; off <<= 1) {
            uint32_t v = 0;
            if (tid < 256) {
                v = seg[tid];
                if (tid + off < 256) v += seg[tid + off];
            }
            __syncthreads();
            if (tid < 256) seg[tid] = v;
            __syncthreads();
        }
        if (tid < 256) {
            uint32_t St  = seg[tid];
            uint32_t St1 = (tid < 255) ? seg[tid + 1] : 0u;
            if (St >= K_PRE && St1 < K_PRE) {     // exactly one thread
                uint32_t c2 = St1;
                uint32_t bstar = 0u;
                for (int q = 15; q >= 0; q--) {
                    c2 += lh[tid * 16 + q];
                    if (c2 >= K_PRE) { bstar = (uint32_t)(tid * 16 + q); break; }
                }
                sh[4400] = bstar;
            }
            if (tid == 0 && seg[0] < K_PRE) sh[4400] = 0u;
        }
        __syncthreads();
        uint32_t bstar = sh[4400];
        if (gtid < N_TOT) {
            uint32_t key = p.keys[gtid];
            if ((key >> 20) >= bstar) {
                uint32_t pos = atomicAdd(p.meta + 1, 1u);
                if (pos < CAP) p.cand[pos] = ((uint64_t)key << 32) | (uint32_t)(~(uint32_t)gtid);
            }
        }
    }
    grid.sync();                                                    // S2

    // ---------------- P3: rank by score (16 cands/block) + props/ykey --------
    {
        uint32_t (*part)[G] = (uint32_t(*)[G])sh;   // [16 waves][16]
        uint32_t C = p.meta[1];
        if (C > CAP) C = CAP;
        uint32_t nGroups = (C + G - 1) / G;
        int wave = tid >> 6, lane = tid & 63;
        for (uint32_t g = bid; g < nGroups; g += NB) {
            uint32_t b = g * G;
            uint64_t m[G];
            uint32_t cnt[G];
            #pragma unroll
            for (int q = 0; q < G; q++) {
                m[q] = (b + q < C) ? p.cand[b + q] : ~0ull;
                cnt[q] = 0u;
            }
            for (uint32_t j0 = 0; j0 < C; j0 += NT * 4) {
                uint32_t ja = j0 + tid, jb = ja + NT, jc = ja + 2 * NT, jd = ja + 3 * NT;
                uint64_t ka = (ja < C) ? p.cand[ja] : 0ull;
                uint64_t kb = (jb < C) ? p.cand[jb] : 0ull;
                uint64_t kc = (jc < C) ? p.cand[jc] : 0ull;
                uint64_t kd = (jd < C) ? p.cand[jd] : 0ull;
                #pragma unroll
                for (int q = 0; q < G; q++)
                    cnt[q] += (uint32_t)(ka > m[q]) + (uint32_t)(kb > m[q])
                            + (uint32_t)(kc > m[q]) + (uint32_t)(kd > m[q]);
            }
            #pragma unroll
            for (int q = 0; q < G; q++) cnt[q] = waveReduceSum(cnt[q]);
            if (lane == 0) {
                #pragma unroll
                for (int q = 0; q < G; q++) part[wave][q] = cnt[q];
            }
            __syncthreads();
            if (tid < G && b + tid < C) {
                uint32_t r = 0;
                #pragma unroll
                for (int w = 0; w < 16; w++) r += part[w][tid];
                if (r < K_PRE) {
                    int idx = (int)(~((uint32_t)p.cand[b + tid]));
                    float px1, py1, pw, ph;
                    compute_box(idx, p.deltas, px1, py1, pw, ph);
                    p.P[r] = make_float4(px1, py1, pw, ph);
                    float y2 = py1 + ph;
                    p.yk[r] = ((uint64_t)__float_as_uint(y2) << 32) | (uint32_t)(~r);
                }
            }
            __syncthreads();
        }
    }
    grid.sync();                                                    // S3

    // ---------------- P4: stable y2-desc rank + div-free boundary ------------
    // pred( round(d/area) >= 0.7f ) <=> d >= Bnd; M = 0.7f - 2^-25; M*area
    // exact in double; Bnd = smallest fp32 > M*area.
    {
        uint32_t (*part)[G] = (uint32_t(*)[G])sh;
        int wave = tid >> 6, lane = tid & 63;
        for (uint32_t g = bid; g < (K_PRE / G); g += NB) {   // 375 groups
            uint32_t b = g * G;
            uint64_t m[G];
            uint32_t cnt[G];
            #pragma unroll
            for (int q = 0; q < G; q++) {
                m[q] = p.yk[b + q];
                cnt[q] = 0u;
            }
            for (uint32_t j0 = 0; j0 < K_PRE; j0 += NT * 4) {
                uint32_t ja = j0 + tid, jb = ja + NT, jc = ja + 2 * NT, jd = ja + 3 * NT;
                uint64_t ka = (ja < K_PRE) ? p.yk[ja] : 0ull;
                uint64_t kb = (jb < K_PRE) ? p.yk[jb] : 0ull;
                uint64_t kc = (jc < K_PRE) ? p.yk[jc] : 0ull;
                uint64_t kd = (jd < K_PRE) ? p.yk[jd] : 0ull;
                #pragma unroll
                for (int q = 0; q < G; q++)
                    cnt[q] += (uint32_t)(ka > m[q]) + (uint32_t)(kb > m[q])
                            + (uint32_t)(kc > m[q]) + (uint32_t)(kd > m[q]);
            }
            #pragma unroll
            for (int q = 0; q < G; q++) cnt[q] = waveReduceSum(cnt[q]);
            if (lane == 0) {
                #pragma unroll
                for (int q = 0; q < G; q++) part[wave][q] = cnt[q];
            }
            __syncthreads();
            if (tid < G) {
                uint32_t r = 0;
                #pragma unroll
                for (int w = 0; w < 16; w++) r += part[w][tid];
                float4 pp = p.P[b + tid];
                p.OP[r] = pp;
                float x1 = pp.x, y1 = pp.y;
                float x2 = x1 + pp.z, y2 = y1 + pp.w;
                float area = fmaxf((x2 - x1) * (y2 - y1), 1e-6f);
                p.Q[r] = make_float4(x1, y1, x2, y2);
                const double Mc = (double)0.7f - 0x1.0p-25;
                double c = Mc * (double)area;       // exact
                float Bf = (float)c;
                if (!((double)Bf > c)) Bf = __int_as_float(__float_as_int(Bf) + 1);
                p.Bnd[r] = Bf;
            }
            __syncthreads();
        }
    }
    grid.sync();                                                    // S4

    // ---------------- P5: suppression bitmask (1024 rows x 128 cols tiles) ---
    {
        float4* qs = (float4*)sh;          // 128 * 16 B
        float*  bs = (float*)(sh + 512);   // 128 * 4 B
        for (int t = bid; t < ROWB2 * COLB; t += NB) {     // 282 tiles
            int rb = t % ROWB2, cb = t / ROWB2;
            int i  = rb * NT + tid;
            int c0 = cb * CT;
            int ncols = min(CT, K_PRE - c0);
            __syncthreads();                               // prior tile reads done
            if (tid < ncols) {
                qs[tid] = p.Q[c0 + tid];
                bs[tid] = p.Bnd[c0 + tid];
            }
            __syncthreads();
            bool rowok = (i < K_PRE);
            float4 qi = rowok ? p.Q[i] : make_float4(0.f, 0.f, 0.f, 0.f);
            int nw = (ncols + 31) >> 5;
            for (int w = 0; w < nw; w++) {
                uint32_t bits = 0u;
                int jb = w * 32;
                int jn = min(32, ncols - jb);
                #pragma unroll 8
                for (int b = 0; b < jn; b++) {
                    int j = jb + b;
                    float4 qj = qs[j];
                    float iw = fminf(qi.z, qj.z) - fmaxf(qi.x, qj.x) + 1.0f;
                    iw = fmaxf(iw, 0.0f);
                    float ih = fminf(qi.w, qj.w) - fmaxf(qi.y, qj.y) + 1.0f;
                    ih = fmaxf(ih, 0.0f);
                    float d = iw * ih;
                    bits |= (d >= bs[j]) ? (1u << b) : 0u;
                }
                if (rowok) {
                    int gj = c0 + jb;
                    uint32_t selfo = (uint32_t)(i - gj);
                    if (selfo < 32u) bits &= ~(1u << selfo);
                    p.mask[(size_t)i * MW + (gj >> 5)] = bits;
                }
            }
        }
    }
    grid.sync();                                                    // S5

    // ---------------- P6: serial active scan + validity + emit (block 0) -----
    // R13-verbatim logic; waves 4..15 of block 0 just pass the barriers.
    if (bid == 0) {
        uint32_t* rem  = sh;          // [0..187]
        uint32_t* sidx = sh + 192;    // [192..255]
        uint32_t* svL  = sh + 256;    // [256..443]
        uint32_t* pref = sh + 448;    // [448..635]
        // nsSh at sh[640]
        for (int i = tid; i < MW; i += NT) rem[i] = 0u;
        __syncthreads();
        uint2 mr = make_uint2(0u, 0u);
        if (tid < 64) mr = *(const uint2*)(p.mask + (size_t)tid * MW);   // chunk 0
        for (int c = 0; c < NCHUNK; c++) {
            int base = c * 64;
            int rows = min(64, K_PRE - base);
            if (tid < 64) {
                uint64_t v = ~(((uint64_t)rem[2 * c + 1] << 32) | (uint64_t)rem[2 * c]);
                if (rows < 64) v &= ((1ull << rows) - 1ull);
                uint64_t work = v, surv = 0ull;
                while (work) {                      // leader iteration
                    int k = __ffsll((unsigned long long)work) - 1;
                    surv |= 1ull << k;
                    uint64_t rowk =
                        ((uint64_t)(uint32_t)__builtin_amdgcn_readlane((int)mr.y, k) << 32)
                      |  (uint64_t)(uint32_t)__builtin_amdgcn_readlane((int)mr.x, k);
                    work &= ~rowk;
                    work &= ~(1ull << k);
                }
                uint32_t ns = (uint32_t)__popcll(surv);
                if (tid == 0) {
                    svL[2 * c]     = (uint32_t)surv;
                    svL[2 * c + 1] = (uint32_t)(surv >> 32);
                    sh[640] = ns;
                }
                if ((surv >> tid) & 1ull) {
                    uint32_t pr = __popcll(surv & ((1ull << tid) - 1ull));
                    sidx[pr] = (uint32_t)(base + tid);
                }
                if (surv) {         // pad sidx to x16 with first survivor (OR-idempotent)
                    uint32_t nsPad = (ns + 15u) & ~15u;
                    uint32_t first = (uint32_t)base +
                                     (uint32_t)(__ffsll((unsigned long long)surv) - 1);
                    if ((uint32_t)tid >= ns && (uint32_t)tid < nsPad) sidx[tid] = first;
                }
                if (c + 1 < NCHUNK)
                    mr = *(const uint2*)(p.mask + (size_t)(base + 64 + tid) * MW + 2 * (c + 1));
            }
            __syncthreads();
            int w = tid - 64;
            if (w >= 0 && w < MW) {
                uint32_t nsPad = (sh[640] + 15u) & ~15u;
                uint32_t acc = rem[w];
                for (uint32_t t2 = 0; t2 < nsPad; t2 += 16) {
                    uint32_t r[16];
                    #pragma unroll
                    for (int q = 0; q < 16; q++)
                        r[q] = p.mask[(size_t)sidx[t2 + q] * MW + w];
                    uint32_t o = 0u;
                    #pragma unroll
                    for (int q = 0; q < 16; q++) o |= r[q];
                    acc |= o;
                }
                rem[w] = acc;
            }
            __syncthreads();
        }
        if (tid < MW) {
            uint32_t vv = svL[tid] & ~rem[tid];
            if (tid == MW - 1) vv &= 0xFFFFu;
            rem[tid] = vv;
        }
        __syncthreads();
        if (tid == 0) {
            uint32_t run = 0;
            for (int w2 = 0; w2 < MW; w2++) { pref[w2] = run; run += (uint32_t)__popc(rem[w2]); }
        }
        __syncthreads();
        if (tid < MW) {
            uint32_t b = rem[tid];
            uint32_t r = pref[tid];
            int basebit = tid * 32;
            while (b && r < K_POST) {
                int bit = __ffs(b) - 1;
                b &= b - 1u;
                float4 pp = p.OP[basebit + bit];
                *(float4*)(p.out + (size_t)r * 4) = pp;
                r++;
            }
        }
    }
}

extern "C" void kernel_launch(void* const* d_in, const int* in_sizes, int n_in,
                              void* d_out, int out_size, void* d_ws, size_t ws_size,
                              hipStream_t stream) {
    (void)in_sizes; (void)n_in; (void)out_size; (void)ws_size;
    char* ws = (char*)d_ws;
    size_t off = 0;
    auto alloc = [&](size_t bytes) -> void* {
        void* pp = ws + off;
        off += (bytes + 255) & ~(size_t)255;
        return pp;
    };
    Params p;
    p.scores = (const float*)d_in[0];
    p.deltas = (const float*)d_in[1];
    p.out    = (float*)d_out;
    p.hist  = (uint32_t*)alloc(4096 * 4);
    p.meta  = (uint32_t*)alloc(64);
    p.keys  = (uint32_t*)alloc((size_t)N_TOT * 4);
    p.cand  = (uint64_t*)alloc((size_t)CAP * 8);
    p.P     = (float4*)alloc((size_t)K_PRE * 16);
    p.yk    = (uint64_t*)alloc((size_t)K_PRE * 8);
    p.OP    = (float4*)alloc((size_t)K_PRE * 16);
    p.Q     = (float4*)alloc((size_t)K_PRE * 16);
    p.Bnd   = (float*)alloc((size_t)K_PRE * 4);
    p.mask  = (uint32_t*)alloc((size_t)ROWS_PAD * MW * 4);   // ~4.5 MB

    void* args[] = { (void*)&p };
    hipLaunchCooperativeKernel((void*)k_all, dim3(NB), dim3(NT), args, 0, stream);
}

// Round 16
// 355.630 us; speedup vs baseline: 1.8894x; 1.0615x over previous
//
#include <hip/hip_runtime.h>
#include <hip/hip_cooperative_groups.h>
#include <cstdint>
#include <cstddef>

namespace cg = cooperative_groups;

#define N_TOT   147456      // 9*128*128
#define K_PRE   6000
#define K_POST  300
#define CAP     32768       // candidate cap (expected ~9.2K)
#define MW      188         // 6016 bits per mask row -> 188 u32 words
#define ROWS_PAD 6016
#define NCHUNK  94
#define CT      128         // mask columns per tile
#define ROWB2   6           // ceil(6000/1024) row blocks in P5
#define COLB    47
#define G       8           // candidates ranked per BLOCK (8: fits 64-VGPR cap, no spill)
#define NB      256         // cooperative grid (validated R5/R15)
#define NT      1024        // threads/block

struct Params {
    const float* scores; const float* deltas; float* out;
    uint32_t* hist; uint32_t* meta;
    uint32_t* keys; uint64_t* cand;
    float4* P; uint64_t* yk; float4* OP; float4* Q; float* Bnd;
    uint32_t* mask;
};

__constant__ float c_sizes[9] = {4.f,8.f,12.f,16.f,24.f,32.f,48.f,64.f,96.f};

// Bit-exact replication of reference box math (anchor + delta, clip).
__device__ __forceinline__ void compute_box(int idx, const float* __restrict__ deltas,
                                            float& px1, float& py1, float& pw, float& ph) {
    int a   = idx >> 14;
    int rem = idx & 16383;
    int h   = rem >> 7;
    int w   = rem & 127;
    float s    = c_sizes[a];
    float half = s * 0.5f;
    const float4 d = *(const float4*)(deltas + (size_t)a * 65536 + (size_t)rem * 4);
    float b0 = (((float)h + 0.5f) - half) + d.x;
    float b1 = (((float)w + 0.5f) - half) + d.y;
    float b2 = s + d.z;
    float b3 = s + d.w;
    b0 = fmaxf(b0, 0.0f); b1 = fmaxf(b1, 0.0f);
    b2 = fmaxf(b2, 0.0f); b3 = fmaxf(b3, 0.0f);
    float x1 = b0, y1 = b1;
    float x2 = b0 + b2, y2 = b1 + b3;
    x1 = fminf(x1, 128.0f); y1 = fminf(y1, 128.0f);
    x2 = fminf(x2, 128.0f); y2 = fminf(y2, 128.0f);
    px1 = x1; py1 = y1; pw = x2 - x1; ph = y2 - y1;
}

__device__ __forceinline__ uint32_t waveReduceSum(uint32_t v) {
    #pragma unroll
    for (int o = 32; o > 0; o >>= 1) v += __shfl_xor(v, o, 64);
    return v;
}

__global__ void __launch_bounds__(NT) k_all(Params p) {
    __shared__ __align__(16) uint32_t sh[4608];   // 18.4 KB, aliased per phase
    cg::grid_group grid = cg::this_grid();
    const int tid  = threadIdx.x;
    const int bid  = blockIdx.x;
    const int gtid = bid * NT + tid;              // 0..262143

    // ---------------- P0: zero out/hist/meta (replaces host memset) ----------
    if (gtid < 4096) p.hist[gtid] = 0u;
    if (gtid < 16)   p.meta[gtid] = 0u;
    if (gtid < K_POST * 4) p.out[gtid] = 0.0f;
    grid.sync();                                                    // S0

    // ---------------- P1: keys + histogram ----------------
    for (int i = tid; i < 4096; i += NT) sh[i] = 0u;
    __syncthreads();
    if (gtid < N_TOT) {
        float px1, py1, pw, ph;
        compute_box(gtid, p.deltas, px1, py1, pw, ph);
        bool keep = (pw >= 3.0f) && (ph >= 3.0f);
        uint32_t key = keep ? __float_as_uint(p.scores[gtid]) : 0u;
        p.keys[gtid] = key;
        atomicAdd(&sh[key >> 20], 1u);
    }
    __syncthreads();
    for (int i = tid; i < 4096; i += NT) {
        uint32_t v = sh[i];
        if (v) atomicAdd(&p.hist[i], v);
    }
    grid.sync();                                                    // S1

    // ---------------- P2: per-block findbin (suffix-scan) + compact ----------
    {
        uint32_t* lh  = sh;          // [0..4095]
        uint32_t* seg = sh + 4096;   // [4096..4351]
        // bstar at sh[4400] -- distinct from seg (R14 alias race fixed)
        for (int i = tid; i < 4096; i += NT) lh[i] = p.hist[i];
        __syncthreads();
        if (tid < 256) {
            uint32_t s = 0;
            #pragma unroll
            for (int q = 0; q < 16; q++) s += lh[tid * 16 + q];
            seg[tid] = s;
        }
        __syncthreads();
        for (int off = 1; off < 256; off <<= 1) {
            uint32_t v = 0;
            if (tid < 256) {
                v = seg[tid];
                if (tid + off < 256) v += seg[tid + off];
            }
            __syncthreads();
            if (tid < 256) seg[tid] = v;
            __syncthreads();
        }
        if (tid < 256) {
            uint32_t St  = seg[tid];
            uint32_t St1 = (tid < 255) ? seg[tid + 1] : 0u;
            if (St >= K_PRE && St1 < K_PRE) {     // exactly one thread
                uint32_t c2 = St1;
                uint32_t bstar = 0u;
                for (int q = 15; q >= 0; q--) {
                    c2 += lh[tid * 16 + q];
                    if (c2 >= K_PRE) { bstar = (uint32_t)(tid * 16 + q); break; }
                }
                sh[4400] = bstar;
            }
            if (tid == 0 && seg[0] < K_PRE) sh[4400] = 0u;
        }
        __syncthreads();
        uint32_t bstar = sh[4400];
        if (gtid < N_TOT) {
            uint32_t key = p.keys[gtid];
            if ((key >> 20) >= bstar) {
                uint32_t pos = atomicAdd(p.meta + 1, 1u);
                if (pos < CAP) p.cand[pos] = ((uint64_t)key << 32) | (uint32_t)(~(uint32_t)gtid);
            }
        }
    }
    grid.sync();                                                    // S2

    // ---------------- P3: rank by score (8 cands/block) + props/ykey ---------
    {
        uint32_t (*part)[G] = (uint32_t(*)[G])sh;   // [16 waves][8]
        uint32_t C = p.meta[1];
        if (C > CAP) C = CAP;
        uint32_t nGroups = (C + G - 1) / G;
        int wave = tid >> 6, lane = tid & 63;
        for (uint32_t g = bid; g < nGroups; g += NB) {
            uint32_t b = g * G;
            uint64_t m[G];
            uint32_t cnt[G];
            #pragma unroll
            for (int q = 0; q < G; q++) {
                m[q] = (b + q < C) ? p.cand[b + q] : ~0ull;
                cnt[q] = 0u;
            }
            for (uint32_t j0 = 0; j0 < C; j0 += NT * 4) {
                uint32_t ja = j0 + tid, jb = ja + NT, jc = ja + 2 * NT, jd = ja + 3 * NT;
                uint64_t ka = (ja < C) ? p.cand[ja] : 0ull;
                uint64_t kb = (jb < C) ? p.cand[jb] : 0ull;
                uint64_t kc = (jc < C) ? p.cand[jc] : 0ull;
                uint64_t kd = (jd < C) ? p.cand[jd] : 0ull;
                #pragma unroll
                for (int q = 0; q < G; q++)
                    cnt[q] += (uint32_t)(ka > m[q]) + (uint32_t)(kb > m[q])
                            + (uint32_t)(kc > m[q]) + (uint32_t)(kd > m[q]);
            }
            #pragma unroll
            for (int q = 0; q < G; q++) cnt[q] = waveReduceSum(cnt[q]);
            if (lane == 0) {
                #pragma unroll
                for (int q = 0; q < G; q++) part[wave][q] = cnt[q];
            }
            __syncthreads();
            if (tid < G && b + tid < C) {
                uint32_t r = 0;
                #pragma unroll
                for (int w = 0; w < 16; w++) r += part[w][tid];
                if (r < K_PRE) {
                    int idx = (int)(~((uint32_t)p.cand[b + tid]));
                    float px1, py1, pw, ph;
                    compute_box(idx, p.deltas, px1, py1, pw, ph);
                    p.P[r] = make_float4(px1, py1, pw, ph);
                    float y2 = py1 + ph;
                    p.yk[r] = ((uint64_t)__float_as_uint(y2) << 32) | (uint32_t)(~r);
                }
            }
            __syncthreads();
        }
    }
    grid.sync();                                                    // S3

    // ---------------- P4: stable y2-desc rank + div-free boundary ------------
    // pred( round(d/area) >= 0.7f ) <=> d >= Bnd; M = 0.7f - 2^-25; M*area
    // exact in double; Bnd = smallest fp32 > M*area.
    {
        uint32_t (*part)[G] = (uint32_t(*)[G])sh;
        int wave = tid >> 6, lane = tid & 63;
        for (uint32_t g = bid; g < (K_PRE / G); g += NB) {   // 750 groups
            uint32_t b = g * G;
            uint64_t m[G];
            uint32_t cnt[G];
            #pragma unroll
            for (int q = 0; q < G; q++) {
                m[q] = p.yk[b + q];
                cnt[q] = 0u;
            }
            for (uint32_t j0 = 0; j0 < K_PRE; j0 += NT * 4) {
                uint32_t ja = j0 + tid, jb = ja + NT, jc = ja + 2 * NT, jd = ja + 3 * NT;
                uint64_t ka = (ja < K_PRE) ? p.yk[ja] : 0ull;
                uint64_t kb = (jb < K_PRE) ? p.yk[jb] : 0ull;
                uint64_t kc = (jc < K_PRE) ? p.yk[jc] : 0ull;
                uint64_t kd = (jd < K_PRE) ? p.yk[jd] : 0ull;
                #pragma unroll
                for (int q = 0; q < G; q++)
                    cnt[q] += (uint32_t)(ka > m[q]) + (uint32_t)(kb > m[q])
                            + (uint32_t)(kc > m[q]) + (uint32_t)(kd > m[q]);
            }
            #pragma unroll
            for (int q = 0; q < G; q++) cnt[q] = waveReduceSum(cnt[q]);
            if (lane == 0) {
                #pragma unroll
                for (int q = 0; q < G; q++) part[wave][q] = cnt[q];
            }
            __syncthreads();
            if (tid < G) {
                uint32_t r = 0;
                #pragma unroll
                for (int w = 0; w < 16; w++) r += part[w][tid];
                float4 pp = p.P[b + tid];
                p.OP[r] = pp;
                float x1 = pp.x, y1 = pp.y;
                float x2 = x1 + pp.z, y2 = y1 + pp.w;
                float area = fmaxf((x2 - x1) * (y2 - y1), 1e-6f);
                p.Q[r] = make_float4(x1, y1, x2, y2);
                const double Mc = (double)0.7f - 0x1.0p-25;
                double c = Mc * (double)area;       // exact
                float Bf = (float)c;
                if (!((double)Bf > c)) Bf = __int_as_float(__float_as_int(Bf) + 1);
                p.Bnd[r] = Bf;
            }
            __syncthreads();
        }
    }
    grid.sync();                                                    // S4

    // ---------------- P5: suppression bitmask (1024 rows x 128 cols tiles) ---
    {
        float4* qs = (float4*)sh;          // 128 * 16 B
        float*  bs = (float*)(sh + 512);   // 128 * 4 B
        for (int t = bid; t < ROWB2 * COLB; t += NB) {     // 282 tiles
            int rb = t % ROWB2, cb = t / ROWB2;
            int i  = rb * NT + tid;
            int c0 = cb * CT;
            int ncols = min(CT, K_PRE - c0);
            __syncthreads();                               // prior tile reads done
            if (tid < ncols) {
                qs[tid] = p.Q[c0 + tid];
                bs[tid] = p.Bnd[c0 + tid];
            }
            __syncthreads();
            bool rowok = (i < K_PRE);
            float4 qi = rowok ? p.Q[i] : make_float4(0.f, 0.f, 0.f, 0.f);
            int nw = (ncols + 31) >> 5;
            for (int w = 0; w < nw; w++) {
                uint32_t bits = 0u;
                int jb = w * 32;
                int jn = min(32, ncols - jb);
                #pragma unroll 8
                for (int b = 0; b < jn; b++) {
                    int j = jb + b;
                    float4 qj = qs[j];
                    float iw = fminf(qi.z, qj.z) - fmaxf(qi.x, qj.x) + 1.0f;
                    iw = fmaxf(iw, 0.0f);
                    float ih = fminf(qi.w, qj.w) - fmaxf(qi.y, qj.y) + 1.0f;
                    ih = fmaxf(ih, 0.0f);
                    float d = iw * ih;
                    bits |= (d >= bs[j]) ? (1u << b) : 0u;
                }
                if (rowok) {
                    int gj = c0 + jb;
                    uint32_t selfo = (uint32_t)(i - gj);
                    if (selfo < 32u) bits &= ~(1u << selfo);
                    p.mask[(size_t)i * MW + (gj >> 5)] = bits;
                }
            }
        }
    }
    grid.sync();                                                    // S5

    // ---------------- P6: serial active scan + validity + emit (block 0) -----
    if (bid == 0) {
        uint32_t* rem  = sh;          // [0..187]
        uint32_t* sidx = sh + 192;    // [192..255]
        uint32_t* svL  = sh + 256;    // [256..443]
        uint32_t* pref = sh + 448;    // [448..635]
        // nsSh at sh[640]
        for (int i = tid; i < MW; i += NT) rem[i] = 0u;
        __syncthreads();
        uint2 mr = make_uint2(0u, 0u);
        if (tid < 64) mr = *(const uint2*)(p.mask + (size_t)tid * MW);   // chunk 0
        for (int c = 0; c < NCHUNK; c++) {
            int base = c * 64;
            int rows = min(64, K_PRE - base);
            if (tid < 64) {
                uint64_t v = ~(((uint64_t)rem[2 * c + 1] << 32) | (uint64_t)rem[2 * c]);
                if (rows < 64) v &= ((1ull << rows) - 1ull);
                uint64_t work = v, surv = 0ull;
                while (work) {                      // leader iteration
                    int k = __ffsll((unsigned long long)work) - 1;
                    surv |= 1ull << k;
                    uint64_t rowk =
                        ((uint64_t)(uint32_t)__builtin_amdgcn_readlane((int)mr.y, k) << 32)
                      |  (uint64_t)(uint32_t)__builtin_amdgcn_readlane((int)mr.x, k);
                    work &= ~rowk;
                    work &= ~(1ull << k);
                }
                uint32_t ns = (uint32_t)__popcll(surv);
                if (tid == 0) {
                    svL[2 * c]     = (uint32_t)surv;
                    svL[2 * c + 1] = (uint32_t)(surv >> 32);
                    sh[640] = ns;
                }
                if ((surv >> tid) & 1ull) {
                    uint32_t pr = __popcll(surv & ((1ull << tid) - 1ull));
                    sidx[pr] = (uint32_t)(base + tid);
                }
                if (surv) {         // pad sidx to x16 with first survivor (OR-idempotent)
                    uint32_t nsPad = (ns + 15u) & ~15u;
                    uint32_t first = (uint32_t)base +
                                     (uint32_t)(__ffsll((unsigned long long)surv) - 1);
                    if ((uint32_t)tid >= ns && (uint32_t)tid < nsPad) sidx[tid] = first;
                }
                if (c + 1 < NCHUNK)
                    mr = *(const uint2*)(p.mask + (size_t)(base + 64 + tid) * MW + 2 * (c + 1));
            }
            __syncthreads();
            int w = tid - 64;
            if (w >= 0 && w < MW) {
                uint32_t nsPad = (sh[640] + 15u) & ~15u;
                uint32_t acc = rem[w];
                for (uint32_t t2 = 0; t2 < nsPad; t2 += 16) {
                    uint32_t r[16];
                    #pragma unroll
                    for (int q = 0; q < 16; q++)
                        r[q] = p.mask[(size_t)sidx[t2 + q] * MW + w];
                    uint32_t o = 0u;
                    #pragma unroll
                    for (int q = 0; q < 16; q++) o |= r[q];
                    acc |= o;
                }
                rem[w] = acc;
            }
            __syncthreads();
        }
        if (tid < MW) {
            uint32_t vv = svL[tid] & ~rem[tid];
            if (tid == MW - 1) vv &= 0xFFFFu;
            rem[tid] = vv;
        }
        __syncthreads();
        if (tid == 0) {
            uint32_t run = 0;
            for (int w2 = 0; w2 < MW; w2++) { pref[w2] = run; run += (uint32_t)__popc(rem[w2]); }
        }
        __syncthreads();
        if (tid < MW) {
            uint32_t b = rem[tid];
            uint32_t r = pref[tid];
            int basebit = tid * 32;
            while (b && r < K_POST) {
                int bit = __ffs(b) - 1;
                b &= b - 1u;
                float4 pp = p.OP[basebit + bit];
                *(float4*)(p.out + (size_t)r * 4) = pp;
                r++;
            }
        }
    }
}

extern "C" void kernel_launch(void* const* d_in, const int* in_sizes, int n_in,
                              void* d_out, int out_size, void* d_ws, size_t ws_size,
                              hipStream_t stream) {
    (void)in_sizes; (void)n_in; (void)out_size; (void)ws_size;
    char* ws = (char*)d_ws;
    size_t off = 0;
    auto alloc = [&](size_t bytes) -> void* {
        void* pp = ws + off;
        off += (bytes + 255) & ~(size_t)255;
        return pp;
    };
    Params p;
    p.scores = (const float*)d_in[0];
    p.deltas = (const float*)d_in[1];
    p.out    = (float*)d_out;
    p.hist  = (uint32_t*)alloc(4096 * 4);
    p.meta  = (uint32_t*)alloc(64);
    p.keys  = (uint32_t*)alloc((size_t)N_TOT * 4);
    p.cand  = (uint64_t*)alloc((size_t)CAP * 8);
    p.P     = (float4*)alloc((size_t)K_PRE * 16);
    p.yk    = (uint64_t*)alloc((size_t)K_PRE * 8);
    p.OP    = (float4*)alloc((size_t)K_PRE * 16);
    p.Q     = (float4*)alloc((size_t)K_PRE * 16);
    p.Bnd   = (float*)alloc((size_t)K_PRE * 4);
    p.mask  = (uint32_t*)alloc((size_t)ROWS_PAD * MW * 4);   // ~4.5 MB

    void* args[] = { (void*)&p };
    hipLaunchCooperativeKernel((void*)k_all, dim3(NB), dim3(NT), args, 0, stream);
}